// Round 1
// baseline (300.286 us; speedup 1.0000x reference)
//
#include <hip/hip_runtime.h>
#include <hip/hip_bf16.h>

// N=4096, E=1024, H=16, DK=DV=64
// ws layout (bytes):
//   xb    @ 0         8 MB   bf16 [4096][1024]
//   wqt   @ 8 MB      2 MB   bf16 [16][64][1024]  (Wq transposed per head)
//   wkt   @ 10 MB     2 MB
//   wvt   @ 12 MB     2 MB
//   wot   @ 14 MB     2 MB   bf16 [1024 eo][1024 k]  (Wo transposed)
//   Q     @ 16 MB     8 MB   bf16 [16][4096][64]
//   K     @ 24 MB     8 MB   bf16 [16][4096][64]
//   Vt    @ 32 MB     8 MB   bf16 [16][64][4096]  (V transposed)
//   cc    @ 40 MB     8 MB   bf16 [4096][1024]    (concat heads)
// total 48 MB

typedef __attribute__((ext_vector_type(8))) short s16x8;
typedef __attribute__((ext_vector_type(4))) float f32x4;

#define MFMA16(A, B, C) __builtin_amdgcn_mfma_f32_16x16x32_bf16((A), (B), (C), 0, 0, 0)

__device__ __forceinline__ unsigned short f2bf(float f) {
  unsigned int u = __float_as_uint(f);
  unsigned int r = (u + 0x7FFFu + ((u >> 16) & 1u)) >> 16;
  return (unsigned short)r;
}

// ---------------- prep kernels ----------------

__global__ __launch_bounds__(256) void convert_x(const float* __restrict__ x,
                                                 unsigned short* __restrict__ xb) {
  unsigned i = blockIdx.x * 256u + threadIdx.x;  // one float4 per thread
  float4 v = reinterpret_cast<const float4*>(x)[i];
  ushort4 o;
  o.x = f2bf(v.x); o.y = f2bf(v.y); o.z = f2bf(v.z); o.w = f2bf(v.w);
  reinterpret_cast<ushort4*>(xb)[i] = o;
}

// dst[b][c][r] = bf16(src[b][r][c])
__global__ __launch_bounds__(256) void transpose_w(const float* __restrict__ src,
                                                   unsigned short* __restrict__ dst,
                                                   unsigned rows, unsigned cols) {
  unsigned idx = blockIdx.x * 256u + threadIdx.x;
  unsigned rc = rows * cols;
  unsigned b = idx / rc;
  unsigned rem = idx - b * rc;
  unsigned c = rem / rows;
  unsigned r = rem - c * rows;
  dst[idx] = f2bf(src[b * rc + r * cols + c]);
}

// ---------------- QKV projection GEMM ----------------
// grid (32, 48): x = M-tile (128 rows), y = h*3 + mat. block 512 (8 waves, 16 rows each).
// C[128][64] = xb[128][1024] @ W[1024][64]; B staged from W^T (wqt etc).
__global__ __launch_bounds__(512)
void qkv_gemm(const unsigned short* __restrict__ xb,
              const unsigned short* __restrict__ wqt,
              const unsigned short* __restrict__ wkt,
              const unsigned short* __restrict__ wvt,
              unsigned short* __restrict__ Q,
              unsigned short* __restrict__ K,
              unsigned short* __restrict__ Vt) {
  __shared__ char lds[16384 + 8192];
  char* At = lds;           // [128][64] bf16, XOR-swizzled 16B chunks
  char* Bl = lds + 16384;   // [64][64] bf16, swizzled

  const int tid = threadIdx.x;
  const int w = tid >> 6, lane = tid & 63;
  const int lr = lane & 15, lg = lane >> 4;
  const int h = blockIdx.y / 3, mat = blockIdx.y % 3;
  const unsigned short* Bg = (mat == 0 ? wqt : (mat == 1 ? wkt : wvt)) + h * 65536;
  const int m0 = blockIdx.x * 128;

  f32x4 acc[4] = {};

  // fragment LDS offsets (loop-invariant)
  const int arow = w * 16 + lr;
  unsigned aoff[2], boff[4][2];
#pragma unroll
  for (int ks = 0; ks < 2; ++ks)
    aoff[ks] = (unsigned)((arow * 128 + ks * 64 + lg * 16) ^ ((arow & 7) << 4));
#pragma unroll
  for (int n = 0; n < 4; ++n)
#pragma unroll
    for (int ks = 0; ks < 2; ++ks) {
      int br = n * 16 + lr;
      boff[n][ks] = (unsigned)((br * 128 + ks * 64 + lg * 16) ^ ((br & 7) << 4));
    }

  for (int kk = 0; kk < 16; ++kk) {
    // stage A: 1024 chunks of 16B, 2 per thread
#pragma unroll
    for (int i = 0; i < 2; ++i) {
      int c = tid + i * 512;
      int row = c >> 3, c16 = c & 7;
      uint4 v = *reinterpret_cast<const uint4*>(xb + (m0 + row) * 1024 + kk * 64 + c16 * 8);
      *reinterpret_cast<uint4*>(At + ((row * 128 + c16 * 16) ^ ((row & 7) << 4))) = v;
    }
    {  // stage B: 512 chunks, 1 per thread
      int row = tid >> 3, c16 = tid & 7;
      uint4 v = *reinterpret_cast<const uint4*>(Bg + row * 1024 + kk * 64 + c16 * 8);
      *reinterpret_cast<uint4*>(Bl + ((row * 128 + c16 * 16) ^ ((row & 7) << 4))) = v;
    }
    __syncthreads();
    s16x8 af0 = *reinterpret_cast<const s16x8*>(At + aoff[0]);
    s16x8 af1 = *reinterpret_cast<const s16x8*>(At + aoff[1]);
#pragma unroll
    for (int n = 0; n < 4; ++n) {
      acc[n] = MFMA16(af0, *reinterpret_cast<const s16x8*>(Bl + boff[n][0]), acc[n]);
      acc[n] = MFMA16(af1, *reinterpret_cast<const s16x8*>(Bl + boff[n][1]), acc[n]);
    }
    __syncthreads();
  }

  unsigned short* dst = (mat == 0 ? Q : (mat == 1 ? K : Vt));
#pragma unroll
  for (int n = 0; n < 4; ++n)
#pragma unroll
    for (int r = 0; r < 4; ++r) {
      int row = m0 + w * 16 + lg * 4 + r;  // token index
      int col = n * 16 + lr;               // d index
      unsigned short val = f2bf(acc[n][r]);
      if (mat < 2) dst[h * 262144 + row * 64 + col] = val;       // Q/K: [h][n][64]
      else         dst[h * 262144 + col * 4096 + row] = val;     // Vt: [h][64][4096]
    }
}

// ---------------- fused attention (no-max online softmax) ----------------
// grid (32, 16): x = Q-tile (128 rows), y = head. block 512 (8 waves, 16 q-rows each).
__global__ __launch_bounds__(512)
void attn_kernel(const unsigned short* __restrict__ Q,
                 const unsigned short* __restrict__ K,
                 const unsigned short* __restrict__ Vt,
                 unsigned short* __restrict__ cc) {
  __shared__ char lds[8192 + 8192 + 8 * 2304];
  char* Kt = lds;                      // [64 key][64 d] bf16 swizzled
  char* Vl = lds + 8192;               // [64 d][64 key] bf16 swizzled
  const int tid = threadIdx.x;
  const int w = tid >> 6, lane = tid & 63;
  const int lr = lane & 15, lg = lane >> 4;
  char* Pw = lds + 16384 + w * 2304;   // per-wave P: [16 q][72 bf16] stride 144B

  const int h = blockIdx.y;
  const int q0 = blockIdx.x * 128;
  const unsigned short* Qh = Q + h * 262144;
  const unsigned short* Kh = K + h * 262144;
  const unsigned short* Vh = Vt + h * 262144;

  // Q fragments held in registers for the whole kernel
  const int qrow = q0 + w * 16 + lr;
  s16x8 qf0 = *reinterpret_cast<const s16x8*>(Qh + qrow * 64 + lg * 8);
  s16x8 qf1 = *reinterpret_cast<const s16x8*>(Qh + qrow * 64 + 32 + lg * 8);

  f32x4 acc[4] = {};
  float rs0 = 0.f, rs1 = 0.f, rs2 = 0.f, rs3 = 0.f;

  const int srow = tid >> 3, sc16 = tid & 7;
  const unsigned sdst = (unsigned)((srow * 128 + sc16 * 16) ^ ((srow & 7) << 4));
  unsigned foff[4][2];
#pragma unroll
  for (int n = 0; n < 4; ++n)
#pragma unroll
    for (int ks = 0; ks < 2; ++ks) {
      int br = n * 16 + lr;
      foff[n][ks] = (unsigned)((br * 128 + ks * 64 + lg * 16) ^ ((br & 7) << 4));
    }
  const unsigned poff0 = (unsigned)(lr * 144 + lg * 16);
  const unsigned poff1 = poff0 + 64;

  for (int kt = 0; kt < 64; ++kt) {
    // stage K-tile and Vt-tile (512 chunks each, 1 per thread)
    uint4 kv = *reinterpret_cast<const uint4*>(Kh + (kt * 64 + srow) * 64 + sc16 * 8);
    uint4 vv = *reinterpret_cast<const uint4*>(Vh + srow * 4096 + kt * 64 + sc16 * 8);
    *reinterpret_cast<uint4*>(Kt + sdst) = kv;
    *reinterpret_cast<uint4*>(Vl + sdst) = vv;
    __syncthreads();

    // S = Q K^T  (16 q-rows x 64 keys per wave)
    f32x4 s[4] = {};
#pragma unroll
    for (int n = 0; n < 4; ++n) {
      s[n] = MFMA16(qf0, *reinterpret_cast<const s16x8*>(Kt + foff[n][0]), s[n]);
      s[n] = MFMA16(qf1, *reinterpret_cast<const s16x8*>(Kt + foff[n][1]), s[n]);
    }

    // P = exp(S/8), accumulate row-sums, write bf16 P to wave-private LDS
#pragma unroll
    for (int n = 0; n < 4; ++n) {
      float p0 = __expf(s[n][0] * 0.125f);
      float p1 = __expf(s[n][1] * 0.125f);
      float p2 = __expf(s[n][2] * 0.125f);
      float p3 = __expf(s[n][3] * 0.125f);
      rs0 += p0; rs1 += p1; rs2 += p2; rs3 += p3;
      int cb = (n * 16 + lr) * 2;
      *reinterpret_cast<unsigned short*>(Pw + (lg * 4 + 0) * 144 + cb) = f2bf(p0);
      *reinterpret_cast<unsigned short*>(Pw + (lg * 4 + 1) * 144 + cb) = f2bf(p1);
      *reinterpret_cast<unsigned short*>(Pw + (lg * 4 + 2) * 144 + cb) = f2bf(p2);
      *reinterpret_cast<unsigned short*>(Pw + (lg * 4 + 3) * 144 + cb) = f2bf(p3);
    }

    // O += P V  (A-frags from wave-private P, B-frags from Vt tile)
    s16x8 pf0 = *reinterpret_cast<const s16x8*>(Pw + poff0);
    s16x8 pf1 = *reinterpret_cast<const s16x8*>(Pw + poff1);
#pragma unroll
    for (int n = 0; n < 4; ++n) {
      acc[n] = MFMA16(pf0, *reinterpret_cast<const s16x8*>(Vl + foff[n][0]), acc[n]);
      acc[n] = MFMA16(pf1, *reinterpret_cast<const s16x8*>(Vl + foff[n][1]), acc[n]);
    }
    __syncthreads();
  }

  // reduce row-sums across the 16 lanes sharing each q-row group
#pragma unroll
  for (int m = 1; m < 16; m <<= 1) {
    rs0 += __shfl_xor(rs0, m, 64);
    rs1 += __shfl_xor(rs1, m, 64);
    rs2 += __shfl_xor(rs2, m, 64);
    rs3 += __shfl_xor(rs3, m, 64);
  }
  float rsv[4] = {rs0, rs1, rs2, rs3};

#pragma unroll
  for (int n = 0; n < 4; ++n)
#pragma unroll
    for (int r = 0; r < 4; ++r) {
      int row = q0 + w * 16 + lg * 4 + r;
      int col = h * 64 + n * 16 + lr;
      cc[row * 1024 + col] = f2bf(acc[n][r] / rsv[r]);
    }
}

// ---------------- output projection GEMM ----------------
// grid (32, 16): x = M-tile, y = 64-col group of E. block 512.
__global__ __launch_bounds__(512)
void out_gemm(const unsigned short* __restrict__ A,    // cc [4096][1024] bf16
              const unsigned short* __restrict__ Bt,   // wot [1024 eo][1024 k] bf16
              float* __restrict__ out) {
  __shared__ char lds[16384 + 8192];
  char* At = lds;
  char* Bl = lds + 16384;

  const int tid = threadIdx.x;
  const int w = tid >> 6, lane = tid & 63;
  const int lr = lane & 15, lg = lane >> 4;
  const int m0 = blockIdx.x * 128;
  const int n0 = blockIdx.y * 64;
  const unsigned short* Bg = Bt + n0 * 1024;

  f32x4 acc[4] = {};

  const int arow = w * 16 + lr;
  unsigned aoff[2], boff[4][2];
#pragma unroll
  for (int ks = 0; ks < 2; ++ks)
    aoff[ks] = (unsigned)((arow * 128 + ks * 64 + lg * 16) ^ ((arow & 7) << 4));
#pragma unroll
  for (int n = 0; n < 4; ++n)
#pragma unroll
    for (int ks = 0; ks < 2; ++ks) {
      int br = n * 16 + lr;
      boff[n][ks] = (unsigned)((br * 128 + ks * 64 + lg * 16) ^ ((br & 7) << 4));
    }

  for (int kk = 0; kk < 16; ++kk) {
#pragma unroll
    for (int i = 0; i < 2; ++i) {
      int c = tid + i * 512;
      int row = c >> 3, c16 = c & 7;
      uint4 v = *reinterpret_cast<const uint4*>(A + (m0 + row) * 1024 + kk * 64 + c16 * 8);
      *reinterpret_cast<uint4*>(At + ((row * 128 + c16 * 16) ^ ((row & 7) << 4))) = v;
    }
    {
      int row = tid >> 3, c16 = tid & 7;
      uint4 v = *reinterpret_cast<const uint4*>(Bg + row * 1024 + kk * 64 + c16 * 8);
      *reinterpret_cast<uint4*>(Bl + ((row * 128 + c16 * 16) ^ ((row & 7) << 4))) = v;
    }
    __syncthreads();
    s16x8 af0 = *reinterpret_cast<const s16x8*>(At + aoff[0]);
    s16x8 af1 = *reinterpret_cast<const s16x8*>(At + aoff[1]);
#pragma unroll
    for (int n = 0; n < 4; ++n) {
      acc[n] = MFMA16(af0, *reinterpret_cast<const s16x8*>(Bl + boff[n][0]), acc[n]);
      acc[n] = MFMA16(af1, *reinterpret_cast<const s16x8*>(Bl + boff[n][1]), acc[n]);
    }
    __syncthreads();
  }

#pragma unroll
  for (int n = 0; n < 4; ++n)
#pragma unroll
    for (int r = 0; r < 4; ++r) {
      int row = m0 + w * 16 + lg * 4 + r;
      int col = n0 + n * 16 + lr;
      out[row * 1024 + col] = acc[n][r];
    }
}

// ---------------- launcher ----------------

extern "C" void kernel_launch(void* const* d_in, const int* in_sizes, int n_in,
                              void* d_out, int out_size, void* d_ws, size_t ws_size,
                              hipStream_t stream) {
  const float* x  = (const float*)d_in[0];
  const float* Wq = (const float*)d_in[1];
  const float* Wk = (const float*)d_in[2];
  const float* Wv = (const float*)d_in[3];
  const float* Wo = (const float*)d_in[4];
  float* out = (float*)d_out;
  char* ws = (char*)d_ws;

  unsigned short* xb  = (unsigned short*)(ws);
  unsigned short* wqt = (unsigned short*)(ws + 8388608);
  unsigned short* wkt = (unsigned short*)(ws + 10485760);
  unsigned short* wvt = (unsigned short*)(ws + 12582912);
  unsigned short* wot = (unsigned short*)(ws + 14680064);
  unsigned short* Qb  = (unsigned short*)(ws + 16777216);
  unsigned short* Kb  = (unsigned short*)(ws + 25165824);
  unsigned short* Vtb = (unsigned short*)(ws + 33554432);
  unsigned short* cc  = (unsigned short*)(ws + 41943040);

  convert_x<<<4096, 256, 0, stream>>>(x, xb);
  transpose_w<<<4096, 256, 0, stream>>>(Wq, wqt, 1024u, 64u);
  transpose_w<<<4096, 256, 0, stream>>>(Wk, wkt, 1024u, 64u);
  transpose_w<<<4096, 256, 0, stream>>>(Wv, wvt, 1024u, 64u);
  transpose_w<<<4096, 256, 0, stream>>>(Wo, wot, 1024u, 1024u);

  qkv_gemm<<<dim3(32, 48), 512, 0, stream>>>(xb, wqt, wkt, wvt, Qb, Kb, Vtb);
  attn_kernel<<<dim3(32, 16), 512, 0, stream>>>(Qb, Kb, Vtb, cc);
  out_gemm<<<dim3(32, 16), 512, 0, stream>>>(cc, wot, out);
}

// Round 2
// 251.952 us; speedup vs baseline: 1.1918x; 1.1918x over previous
//
#include <hip/hip_runtime.h>
#include <hip/hip_bf16.h>

// N=4096, E=1024, H=16, DK=DV=64
// ws layout (bytes):
//   xb    @ 0         8 MB   bf16 [4096][1024]
//   wqt   @ 8 MB      2 MB   bf16 [16][64][1024]  (Wq^T per head, Q pre-scaled later)
//   wkt   @ 10 MB     2 MB
//   wvt   @ 12 MB     2 MB
//   wot   @ 14 MB     2 MB   bf16 [1024 eo][1024 k]  (Wo transposed)
//   Q     @ 16 MB     8 MB   bf16 [16][4096][64]  (scaled by 0.125*log2e)
//   K     @ 24 MB     8 MB   bf16 [16][4096][64]
//   Vt    @ 32 MB     8 MB   bf16 [16][64][4096]  (V transposed)
//   cc    @ 40 MB     8 MB   bf16 [4096][1024]    (concat heads)

typedef __attribute__((ext_vector_type(8))) short s16x8;
typedef __attribute__((ext_vector_type(4))) float f32x4;
typedef __attribute__((ext_vector_type(16))) float f32x16;

#define MFMA16(A, B, C) __builtin_amdgcn_mfma_f32_16x16x32_bf16((A), (B), (C), 0, 0, 0)
#define MFMA32(A, B, C) __builtin_amdgcn_mfma_f32_32x32x16_bf16((A), (B), (C), 0, 0, 0)

union U8 { s16x8 h; unsigned u[4]; };

__device__ __forceinline__ unsigned short f2bf(float f) {
  unsigned int u = __float_as_uint(f);
  unsigned int r = (u + 0x7FFFu + ((u >> 16) & 1u)) >> 16;
  return (unsigned short)r;
}

__device__ __forceinline__ float expv(float x) {  // 2^x
  float r; asm("v_exp_f32 %0, %1" : "=v"(r) : "v"(x)); return r;
}

__device__ __forceinline__ unsigned cvtpk(float lo, float hi) {
  unsigned d; asm("v_cvt_pk_bf16_f32 %0, %1, %2" : "=v"(d) : "v"(lo), "v"(hi)); return d;
}

// v_permlane32_swap_b32: DST.row[1] <-> SRC.row[0]
// a' = [a.lanes0-31, b.lanes0-31], b' = [a.lanes32-63, b.lanes32-63]
__device__ __forceinline__ void pl32swap(unsigned& a, unsigned& b) {
  asm("v_permlane32_swap_b32 %0, %1" : "+v"(a), "+v"(b));
}

__device__ __forceinline__ void gload16(const void* g, void* l) {
  __builtin_amdgcn_global_load_lds(
      (const __attribute__((address_space(1))) unsigned*)g,
      (__attribute__((address_space(3))) unsigned*)l, 16, 0, 0);
}

// ---------------- prep kernels ----------------

__global__ __launch_bounds__(256) void convert_x(const float* __restrict__ x,
                                                 unsigned short* __restrict__ xb) {
  unsigned i = blockIdx.x * 256u + threadIdx.x;
  float4 v = reinterpret_cast<const float4*>(x)[i];
  ushort4 o;
  o.x = f2bf(v.x); o.y = f2bf(v.y); o.z = f2bf(v.z); o.w = f2bf(v.w);
  reinterpret_cast<ushort4*>(xb)[i] = o;
}

// tiled transpose+cast: src [B][R][C] f32 -> dst [B][C][R] bf16. grid (B, R/64, C/64), 256 thr.
__global__ __launch_bounds__(256)
void transpose_cast(const float* __restrict__ src, unsigned short* __restrict__ dst,
                    int R, int C) {
  __shared__ float t[64][65];
  const int b = blockIdx.x, rt = blockIdx.y, ct = blockIdx.z;
  const int q = threadIdx.x & 3;
  const float* S = src + ((size_t)b * R + rt * 64) * C + ct * 64;
  {
    const int r = threadIdx.x >> 2;
#pragma unroll
    for (int i = 0; i < 4; ++i) {
      float4 v = *reinterpret_cast<const float4*>(S + (size_t)r * C + (i * 4 + q) * 4);
      t[r][(i * 4 + q) * 4 + 0] = v.x;
      t[r][(i * 4 + q) * 4 + 1] = v.y;
      t[r][(i * 4 + q) * 4 + 2] = v.z;
      t[r][(i * 4 + q) * 4 + 3] = v.w;
    }
  }
  __syncthreads();
  const int c = threadIdx.x >> 2;
  unsigned short* D = dst + ((size_t)b * C + ct * 64 + c) * R + rt * 64;
#pragma unroll
  for (int i = 0; i < 2; ++i) {
    int rb = q * 16 + i * 8;
    union { ushort4 v[2]; unsigned short s[8]; } pk;
#pragma unroll
    for (int k = 0; k < 8; ++k) pk.s[k] = f2bf(t[rb + k][c]);
    *reinterpret_cast<ushort4*>(D + rb) = pk.v[0];
    *reinterpret_cast<ushort4*>(D + rb + 4) = pk.v[1];
  }
}

// ---------------- QKV projection GEMM ----------------
// grid (32, 48): x = M-tile (128 rows), y = h*3 + mat. block 512 (8 waves).
__global__ __launch_bounds__(512)
void qkv_gemm(const unsigned short* __restrict__ xb,
              const unsigned short* __restrict__ wqt,
              const unsigned short* __restrict__ wkt,
              const unsigned short* __restrict__ wvt,
              unsigned short* __restrict__ Q,
              unsigned short* __restrict__ K,
              unsigned short* __restrict__ Vt) {
  __shared__ char lds[16384 + 8192];
  char* At = lds;
  char* Bl = lds + 16384;

  const int tid = threadIdx.x;
  const int w = tid >> 6, lane = tid & 63;
  const int lr = lane & 15, lg = lane >> 4;
  const int h = blockIdx.y / 3, mat = blockIdx.y % 3;
  const unsigned short* Bg = (mat == 0 ? wqt : (mat == 1 ? wkt : wvt)) + h * 65536;
  const int m0 = blockIdx.x * 128;

  f32x4 acc[4] = {};

  const int arow = w * 16 + lr;
  unsigned aoff[2], boff[4][2];
#pragma unroll
  for (int ks = 0; ks < 2; ++ks)
    aoff[ks] = (unsigned)((arow * 128 + ks * 64 + lg * 16) ^ ((arow & 7) << 4));
#pragma unroll
  for (int n = 0; n < 4; ++n)
#pragma unroll
    for (int ks = 0; ks < 2; ++ks) {
      int br = n * 16 + lr;
      boff[n][ks] = (unsigned)((br * 128 + ks * 64 + lg * 16) ^ ((br & 7) << 4));
    }

  for (int kk = 0; kk < 16; ++kk) {
#pragma unroll
    for (int i = 0; i < 2; ++i) {
      int c = tid + i * 512;
      int row = c >> 3, c16 = c & 7;
      uint4 v = *reinterpret_cast<const uint4*>(xb + (m0 + row) * 1024 + kk * 64 + c16 * 8);
      *reinterpret_cast<uint4*>(At + ((row * 128 + c16 * 16) ^ ((row & 7) << 4))) = v;
    }
    {
      int row = tid >> 3, c16 = tid & 7;
      uint4 v = *reinterpret_cast<const uint4*>(Bg + row * 1024 + kk * 64 + c16 * 8);
      *reinterpret_cast<uint4*>(Bl + ((row * 128 + c16 * 16) ^ ((row & 7) << 4))) = v;
    }
    __syncthreads();
    s16x8 af0 = *reinterpret_cast<const s16x8*>(At + aoff[0]);
    s16x8 af1 = *reinterpret_cast<const s16x8*>(At + aoff[1]);
#pragma unroll
    for (int n = 0; n < 4; ++n) {
      acc[n] = MFMA16(af0, *reinterpret_cast<const s16x8*>(Bl + boff[n][0]), acc[n]);
      acc[n] = MFMA16(af1, *reinterpret_cast<const s16x8*>(Bl + boff[n][1]), acc[n]);
    }
    __syncthreads();
  }

  // Q gets pre-scaled by 0.125*log2(e) so attention uses v_exp_f32 (2^x) directly.
  const float sc = (mat == 0) ? 0.18033688011112042f : 1.0f;
  unsigned short* dst = (mat == 0 ? Q : (mat == 1 ? K : Vt));
#pragma unroll
  for (int n = 0; n < 4; ++n)
#pragma unroll
    for (int r = 0; r < 4; ++r) {
      int row = m0 + w * 16 + lg * 4 + r;
      int col = n * 16 + lr;
      unsigned short val = f2bf(acc[n][r] * sc);
      if (mat < 2) dst[h * 262144 + row * 64 + col] = val;
      else         dst[h * 262144 + col * 4096 + row] = val;
    }
}

// ---------------- fused attention: 32x32 MFMA, swapped QK^T, in-register softmax ----------------
// 512 blocks x 256 threads (4 waves x 32 q-rows = QBLK 128). KVBLK=64, double-buffered.
__global__ __launch_bounds__(256)
void attn_kernel(const unsigned short* __restrict__ Q,
                 const unsigned short* __restrict__ K,
                 const unsigned short* __restrict__ Vt,
                 unsigned short* __restrict__ cc) {
  __shared__ char smem[2 * 16384 + 512];  // 2 x {K[64][64] bf16 swz, Vt[64][64] bf16 swz} + rsinv
  float* rsf = reinterpret_cast<float*>(smem + 32768);

  const int tid = threadIdx.x;
  const int w = tid >> 6, lane = tid & 63;
  const int l31 = lane & 31, hi = lane >> 5;

  // XCD swizzle: 2 heads per XCD (K/V of 2 heads = 2 MB fits the 4 MB XCD L2)
  const int lin = blockIdx.x;
  const int cxcd = lin & 7, t = lin >> 3;
  const int h = cxcd * 2 + (t >> 5);
  const int q0 = (t & 31) * 128;

  const unsigned short* Qh = Q + h * 262144;
  const unsigned short* Kh = K + h * 262144;
  const unsigned short* Vh = Vt + h * 262144;

  // Q fragments in registers: Q[q0 + w*32 + l31][d = dstep*16 + hi*8 + j]
  s16x8 qf[4];
#pragma unroll
  for (int d = 0; d < 4; ++d)
    qf[d] = *reinterpret_cast<const s16x8*>(Qh + (size_t)(q0 + w * 32 + l31) * 64 + d * 16 + hi * 8);

  // LDS fragment offsets (loop-invariant). XOR swizzle: chunk ^= (row&7).
  unsigned koff[8];   // [kt32*4 + dstep]
#pragma unroll
  for (int k2 = 0; k2 < 2; ++k2)
#pragma unroll
    for (int d = 0; d < 4; ++d) {
      int row = k2 * 32 + l31;
      int ch = (d * 2 + hi) ^ (row & 7);
      koff[k2 * 4 + d] = (unsigned)(row * 128 + ch * 16);
    }
  unsigned voff[8];   // [n*4 + ks]
#pragma unroll
  for (int n = 0; n < 2; ++n)
#pragma unroll
    for (int ks = 0; ks < 4; ++ks) {
      int row = n * 32 + l31;
      int ch = (ks * 2 + hi) ^ (row & 7);
      voff[n * 4 + ks] = (unsigned)(row * 128 + ch * 16);
    }

  // staging: global_load_lds, linear LDS dest + inverse-swizzled global source
  const int so = ((lane & 7) ^ (lane >> 3)) * 8;  // bf16 elems within row
  const int rsub = lane >> 3;
  auto stage = [&](int kt, char* buf) {
    char* bK = buf;
    char* bV = buf + 8192;
    const unsigned short* Ksrc = Kh + (size_t)kt * 4096;
    const unsigned short* Vsrc = Vh + kt * 64;
    gload16(Ksrc + (w * 16 + rsub) * 64 + so,                bK + w * 2048);
    gload16(Ksrc + (w * 16 + 8 + rsub) * 64 + so,            bK + w * 2048 + 1024);
    gload16(Vsrc + (size_t)(w * 16 + rsub) * 4096 + so,      bV + w * 2048);
    gload16(Vsrc + (size_t)(w * 16 + 8 + rsub) * 4096 + so,  bV + w * 2048 + 1024);
  };

  f32x16 o0 = {}, o1 = {};
  float rsl = 0.f;

  stage(0, smem);
  __syncthreads();

  for (int kt = 0; kt < 64; ++kt) {
    const int cur = kt & 1;
    char* cb = smem + cur * 16384;
    if (kt < 63) stage(kt + 1, smem + (cur ^ 1) * 16384);

    const char* bK = cb;
    const char* bV = cb + 8192;

    // S^T = mfma(K, Q): D[key][q], col=l31=q, row=key=(reg&3)+8*(reg>>2)+4*hi
    f32x16 s0 = {}, s1 = {};
#pragma unroll
    for (int d = 0; d < 4; ++d) {
      s16x8 a0 = *reinterpret_cast<const s16x8*>(bK + koff[d]);
      s16x8 a1 = *reinterpret_cast<const s16x8*>(bK + koff[4 + d]);
      s0 = MFMA32(a0, qf[d], s0);
      s1 = MFMA32(a1, qf[d], s1);
    }

    // P = 2^S (scale folded into Q); pack to PV A-frags in-register
    s16x8 pa[4];
    {
      float p[16];
#pragma unroll
      for (int r = 0; r < 16; ++r) { p[r] = expv(s0[r]); rsl += p[r]; }
      unsigned a0 = cvtpk(p[0], p[1]), b0 = cvtpk(p[2], p[3]);
      unsigned a1 = cvtpk(p[4], p[5]), b1 = cvtpk(p[6], p[7]);
      pl32swap(a0, a1); pl32swap(b0, b1);
      U8 f; f.u[0] = a0; f.u[1] = b0; f.u[2] = a1; f.u[3] = b1;
      pa[0] = f.h;
      a0 = cvtpk(p[8], p[9]);  b0 = cvtpk(p[10], p[11]);
      a1 = cvtpk(p[12], p[13]); b1 = cvtpk(p[14], p[15]);
      pl32swap(a0, a1); pl32swap(b0, b1);
      U8 g; g.u[0] = a0; g.u[1] = b0; g.u[2] = a1; g.u[3] = b1;
      pa[1] = g.h;
    }
    {
      float p[16];
#pragma unroll
      for (int r = 0; r < 16; ++r) { p[r] = expv(s1[r]); rsl += p[r]; }
      unsigned a0 = cvtpk(p[0], p[1]), b0 = cvtpk(p[2], p[3]);
      unsigned a1 = cvtpk(p[4], p[5]), b1 = cvtpk(p[6], p[7]);
      pl32swap(a0, a1); pl32swap(b0, b1);
      U8 f; f.u[0] = a0; f.u[1] = b0; f.u[2] = a1; f.u[3] = b1;
      pa[2] = f.h;
      a0 = cvtpk(p[8], p[9]);  b0 = cvtpk(p[10], p[11]);
      a1 = cvtpk(p[12], p[13]); b1 = cvtpk(p[14], p[15]);
      pl32swap(a0, a1); pl32swap(b0, b1);
      U8 g; g.u[0] = a0; g.u[1] = b0; g.u[2] = a1; g.u[3] = b1;
      pa[3] = g.h;
    }

    // O += P V
#pragma unroll
    for (int ks = 0; ks < 4; ++ks) {
      s16x8 v0 = *reinterpret_cast<const s16x8*>(bV + voff[ks]);
      s16x8 v1 = *reinterpret_cast<const s16x8*>(bV + voff[4 + ks]);
      o0 = MFMA32(pa[ks], v0, o0);
      o1 = MFMA32(pa[ks], v1, o1);
    }

    __syncthreads();
  }

  // row-sum across the two lane halves; reciprocal; broadcast via wave-private LDS strip
  float rst = rsl + __shfl_xor(rsl, 32, 64);
  float inv;
  asm("v_rcp_f32 %0, %1" : "=v"(inv) : "v"(rst));
  if (lane < 32) rsf[w * 32 + l31] = inv;
  __syncthreads();

#pragma unroll
  for (int reg = 0; reg < 16; ++reg) {
    int qr = (reg & 3) + 8 * (reg >> 2) + 4 * hi;
    float iv = rsf[w * 32 + qr];
    size_t base = (size_t)(q0 + w * 32 + qr) * 1024 + h * 64 + l31;
    cc[base]      = f2bf(o0[reg] * iv);
    cc[base + 32] = f2bf(o1[reg] * iv);
  }
}

// ---------------- output projection GEMM ----------------
__global__ __launch_bounds__(512)
void out_gemm(const unsigned short* __restrict__ A,
              const unsigned short* __restrict__ Bt,
              float* __restrict__ out) {
  __shared__ char lds[16384 + 8192];
  char* At = lds;
  char* Bl = lds + 16384;

  const int tid = threadIdx.x;
  const int w = tid >> 6, lane = tid & 63;
  const int lr = lane & 15, lg = lane >> 4;
  const int m0 = blockIdx.x * 128;
  const int n0 = blockIdx.y * 64;
  const unsigned short* Bg = Bt + n0 * 1024;

  f32x4 acc[4] = {};

  const int arow = w * 16 + lr;
  unsigned aoff[2], boff[4][2];
#pragma unroll
  for (int ks = 0; ks < 2; ++ks)
    aoff[ks] = (unsigned)((arow * 128 + ks * 64 + lg * 16) ^ ((arow & 7) << 4));
#pragma unroll
  for (int n = 0; n < 4; ++n)
#pragma unroll
    for (int ks = 0; ks < 2; ++ks) {
      int br = n * 16 + lr;
      boff[n][ks] = (unsigned)((br * 128 + ks * 64 + lg * 16) ^ ((br & 7) << 4));
    }

  for (int kk = 0; kk < 16; ++kk) {
#pragma unroll
    for (int i = 0; i < 2; ++i) {
      int c = tid + i * 512;
      int row = c >> 3, c16 = c & 7;
      uint4 v = *reinterpret_cast<const uint4*>(A + (m0 + row) * 1024 + kk * 64 + c16 * 8);
      *reinterpret_cast<uint4*>(At + ((row * 128 + c16 * 16) ^ ((row & 7) << 4))) = v;
    }
    {
      int row = tid >> 3, c16 = tid & 7;
      uint4 v = *reinterpret_cast<const uint4*>(Bg + row * 1024 + kk * 64 + c16 * 8);
      *reinterpret_cast<uint4*>(Bl + ((row * 128 + c16 * 16) ^ ((row & 7) << 4))) = v;
    }
    __syncthreads();
    s16x8 af0 = *reinterpret_cast<const s16x8*>(At + aoff[0]);
    s16x8 af1 = *reinterpret_cast<const s16x8*>(At + aoff[1]);
#pragma unroll
    for (int n = 0; n < 4; ++n) {
      acc[n] = MFMA16(af0, *reinterpret_cast<const s16x8*>(Bl + boff[n][0]), acc[n]);
      acc[n] = MFMA16(af1, *reinterpret_cast<const s16x8*>(Bl + boff[n][1]), acc[n]);
    }
    __syncthreads();
  }

#pragma unroll
  for (int n = 0; n < 4; ++n)
#pragma unroll
    for (int r = 0; r < 4; ++r) {
      int row = m0 + w * 16 + lg * 4 + r;
      int col = n0 + n * 16 + lr;
      out[row * 1024 + col] = acc[n][r];
    }
}

// ---------------- launcher ----------------

extern "C" void kernel_launch(void* const* d_in, const int* in_sizes, int n_in,
                              void* d_out, int out_size, void* d_ws, size_t ws_size,
                              hipStream_t stream) {
  const float* x  = (const float*)d_in[0];
  const float* Wq = (const float*)d_in[1];
  const float* Wk = (const float*)d_in[2];
  const float* Wv = (const float*)d_in[3];
  const float* Wo = (const float*)d_in[4];
  float* out = (float*)d_out;
  char* ws = (char*)d_ws;

  unsigned short* xb  = (unsigned short*)(ws);
  unsigned short* wqt = (unsigned short*)(ws + 8388608);
  unsigned short* wkt = (unsigned short*)(ws + 10485760);
  unsigned short* wvt = (unsigned short*)(ws + 12582912);
  unsigned short* wot = (unsigned short*)(ws + 14680064);
  unsigned short* Qb  = (unsigned short*)(ws + 16777216);
  unsigned short* Kb  = (unsigned short*)(ws + 25165824);
  unsigned short* Vtb = (unsigned short*)(ws + 33554432);
  unsigned short* cc  = (unsigned short*)(ws + 41943040);

  convert_x<<<4096, 256, 0, stream>>>(x, xb);
  transpose_cast<<<dim3(16, 16, 1), 256, 0, stream>>>(Wq, wqt, 1024, 64);
  transpose_cast<<<dim3(16, 16, 1), 256, 0, stream>>>(Wk, wkt, 1024, 64);
  transpose_cast<<<dim3(16, 16, 1), 256, 0, stream>>>(Wv, wvt, 1024, 64);
  transpose_cast<<<dim3(1, 16, 16), 256, 0, stream>>>(Wo, wot, 1024, 1024);

  qkv_gemm<<<dim3(32, 48), 512, 0, stream>>>(xb, wqt, wkt, wvt, Qb, Kb, Vtb);
  attn_kernel<<<512, 256, 0, stream>>>(Qb, Kb, Vtb, cc);
  out_gemm<<<dim3(32, 16), 512, 0, stream>>>(cc, wot, out);
}

// Round 9
// 230.970 us; speedup vs baseline: 1.3001x; 1.0908x over previous
//
#include <hip/hip_runtime.h>
#include <hip/hip_bf16.h>

// N=4096, E=1024, H=16, DK=DV=64
// ws layout (bytes):
//   xb  @ 0      8 MB  bf16 [4096][1024]
//   wqt @ 8 MB   2 MB  bf16 [16][64][1024]
//   wkt @ 10 MB  2 MB
//   wvt @ 12 MB  2 MB
//   wot @ 14 MB  2 MB  bf16 [1024 eo][1024 k]
//   Q   @ 16 MB  8 MB  bf16 [16][4096][64]  (scaled by 0.125*log2e)
//   K   @ 24 MB  8 MB  bf16 [16][4096][64]
//   Vt  @ 32 MB  8 MB  bf16 [16][64][4096]
//   cc  @ 40 MB  8 MB  bf16 [4096][1024]

typedef __attribute__((ext_vector_type(8))) short s16x8;
typedef __attribute__((ext_vector_type(4))) float f32x4;
typedef __attribute__((ext_vector_type(16))) float f32x16;

#define MFMA16(A, B, C) __builtin_amdgcn_mfma_f32_16x16x32_bf16((A), (B), (C), 0, 0, 0)
#define MFMA32(A, B, C) __builtin_amdgcn_mfma_f32_32x32x16_bf16((A), (B), (C), 0, 0, 0)

union U8 { s16x8 h; unsigned u[4]; };

__device__ __forceinline__ unsigned short f2bf(float f) {
  unsigned int u = __float_as_uint(f);
  unsigned int r = (u + 0x7FFFu + ((u >> 16) & 1u)) >> 16;
  return (unsigned short)r;
}

__device__ __forceinline__ float expv(float x) {  // 2^x
  float r; asm("v_exp_f32 %0, %1" : "=v"(r) : "v"(x)); return r;
}

__device__ __forceinline__ unsigned cvtpk(float lo, float hi) {
  unsigned d; asm("v_cvt_pk_bf16_f32 %0, %1, %2" : "=v"(d) : "v"(lo), "v"(hi)); return d;
}

__device__ __forceinline__ void pl32swap(unsigned& a, unsigned& b) {
  asm("v_permlane32_swap_b32 %0, %1" : "+v"(a), "+v"(b));
}

__device__ __forceinline__ void gload16(const void* g, void* l) {
  __builtin_amdgcn_global_load_lds(
      (const __attribute__((address_space(1))) unsigned*)g,
      (__attribute__((address_space(3))) unsigned*)l, 16, 0, 0);
}

// ---------------- prep kernels ----------------

__global__ __launch_bounds__(256) void convert_x(const float* __restrict__ x,
                                                 unsigned short* __restrict__ xb) {
  unsigned i = blockIdx.x * 256u + threadIdx.x;
  float4 v = reinterpret_cast<const float4*>(x)[i];
  ushort4 o;
  o.x = f2bf(v.x); o.y = f2bf(v.y); o.z = f2bf(v.z); o.w = f2bf(v.w);
  reinterpret_cast<ushort4*>(xb)[i] = o;
}

// tiled transpose+cast: src [B][R][C] f32 -> dst [B][C][R] bf16. grid (B, R/64, C/64), 256 thr.
__global__ __launch_bounds__(256)
void transpose_cast(const float* __restrict__ src, unsigned short* __restrict__ dst,
                    int R, int C) {
  __shared__ float t[64][65];
  const int b = blockIdx.x, rt = blockIdx.y, ct = blockIdx.z;
  const int q = threadIdx.x & 3;
  const float* S = src + ((size_t)b * R + rt * 64) * C + ct * 64;
  {
    const int r = threadIdx.x >> 2;
#pragma unroll
    for (int i = 0; i < 4; ++i) {
      float4 v = *reinterpret_cast<const float4*>(S + (size_t)r * C + (i * 4 + q) * 4);
      t[r][(i * 4 + q) * 4 + 0] = v.x;
      t[r][(i * 4 + q) * 4 + 1] = v.y;
      t[r][(i * 4 + q) * 4 + 2] = v.z;
      t[r][(i * 4 + q) * 4 + 3] = v.w;
    }
  }
  __syncthreads();
  const int c = threadIdx.x >> 2;
  unsigned short* D = dst + ((size_t)b * C + ct * 64 + c) * R + rt * 64;
#pragma unroll
  for (int i = 0; i < 2; ++i) {
    int rb = q * 16 + i * 8;
    union { ushort4 v[2]; unsigned short s[8]; } pk;
#pragma unroll
    for (int k = 0; k < 8; ++k) pk.s[k] = f2bf(t[rb + k][c]);
    *reinterpret_cast<ushort4*>(D + rb) = pk.v[0];
    *reinterpret_cast<ushort4*>(D + rb + 4) = pk.v[1];
  }
}

// ---------------- fused QKV projection GEMM (N=192 per head) ----------------
// grid (32 mtiles, 16 heads), 512 thr (8 waves, 2m x 4n over 128x192).
__global__ __launch_bounds__(512, 4)
void qkv_gemm(const unsigned short* __restrict__ xb,
              const unsigned short* __restrict__ wqt,
              const unsigned short* __restrict__ wkt,
              const unsigned short* __restrict__ wvt,
              unsigned short* __restrict__ Q,
              unsigned short* __restrict__ K,
              unsigned short* __restrict__ Vt) {
  __shared__ char lds[16384 + 24576];
  char* At = lds;           // [128][64] bf16, chunk ^= row&7
  char* Bl = lds + 16384;   // [192][64] bf16, chunk ^= row&7

  const int tid = threadIdx.x;
  const int w = tid >> 6, lane = tid & 63;
  const int lr = lane & 15, lg = lane >> 4;
  const int mh = w >> 2, nq = w & 3;  // wave tile: 64m x 48n
  const int h = blockIdx.y;
  const int m0 = blockIdx.x * 128;

  f32x4 acc[4][3] = {};

  unsigned aoff[4][2], boff[3][2];
#pragma unroll
  for (int m = 0; m < 4; ++m) {
    int row = mh * 64 + m * 16 + lr;
#pragma unroll
    for (int ks = 0; ks < 2; ++ks)
      aoff[m][ks] = (unsigned)((row * 128 + ks * 64 + lg * 16) ^ ((row & 7) << 4));
  }
#pragma unroll
  for (int n = 0; n < 3; ++n) {
    int row = nq * 48 + n * 16 + lr;
#pragma unroll
    for (int ks = 0; ks < 2; ++ks)
      boff[n][ks] = (unsigned)((row * 128 + ks * 64 + lg * 16) ^ ((row & 7) << 4));
  }

  for (int kk = 0; kk < 16; ++kk) {
    // stage via global_load_lds: 40 segments of 1KB; wave w does segs w*5..w*5+4
#pragma unroll
    for (int i = 0; i < 5; ++i) {
      int seg = w * 5 + i;
      if (seg < 16) {  // A
        int row = seg * 8 + (lane >> 3);
        int c = lane & 7;
        gload16(xb + (size_t)(m0 + row) * 1024 + kk * 64 + ((c ^ (row & 7)) * 8),
                At + seg * 1024);
      } else {         // B: rows 0..191 = [Wq|Wk|Wv] per head
        int s2 = seg - 16;
        int row = s2 * 8 + (lane >> 3);
        int mat = row >> 6, mr = row & 63;
        const unsigned short* Wb = (mat == 0 ? wqt : (mat == 1 ? wkt : wvt));
        int c = lane & 7;
        gload16(Wb + h * 65536 + mr * 1024 + kk * 64 + ((c ^ (row & 7)) * 8),
                Bl + s2 * 1024);
      }
    }
    __syncthreads();
#pragma unroll
    for (int ks = 0; ks < 2; ++ks) {
      s16x8 af[4], bf[3];
#pragma unroll
      for (int m = 0; m < 4; ++m) af[m] = *reinterpret_cast<const s16x8*>(At + aoff[m][ks]);
#pragma unroll
      for (int n = 0; n < 3; ++n) bf[n] = *reinterpret_cast<const s16x8*>(Bl + boff[n][ks]);
#pragma unroll
      for (int m = 0; m < 4; ++m)
#pragma unroll
        for (int n = 0; n < 3; ++n)
          acc[m][n] = MFMA16(af[m], bf[n], acc[m][n]);
    }
    __syncthreads();
  }

#pragma unroll
  for (int n = 0; n < 3; ++n) {
    int col = nq * 48 + n * 16 + lr;   // 0..191
    int mat = col >> 6, d = col & 63;
    const float sc = (mat == 0) ? 0.18033688011112042f : 1.0f;  // 0.125*log2(e)
    unsigned short* dst = (mat == 0 ? Q : (mat == 1 ? K : Vt));
#pragma unroll
    for (int m = 0; m < 4; ++m)
#pragma unroll
      for (int r = 0; r < 4; ++r) {
        int row = m0 + mh * 64 + m * 16 + lg * 4 + r;
        unsigned short val = f2bf(acc[m][n][r] * sc);
        if (mat < 2) dst[h * 262144 + row * 64 + d] = val;
        else         dst[h * 262144 + d * 4096 + row] = val;
      }
  }
}

// ---------------- fused attention: R2-validated version (passed, 99.9 us) ----------------
// 512 blocks x 256 threads (4 waves x 32 q-rows = QBLK 128). KVBLK=64, double-buffered.
__global__ __launch_bounds__(256)
void attn_kernel(const unsigned short* __restrict__ Q,
                 const unsigned short* __restrict__ K,
                 const unsigned short* __restrict__ Vt,
                 unsigned short* __restrict__ cc) {
  __shared__ char smem[2 * 16384 + 512];  // 2 x {K[64][64] bf16 swz, Vt[64][64] bf16 swz} + rsinv
  float* rsf = reinterpret_cast<float*>(smem + 32768);

  const int tid = threadIdx.x;
  const int w = tid >> 6, lane = tid & 63;
  const int l31 = lane & 31, hi = lane >> 5;

  // XCD swizzle: 2 heads per XCD (K/V of 2 heads = 2 MB fits the 4 MB XCD L2)
  const int lin = blockIdx.x;
  const int cxcd = lin & 7, t = lin >> 3;
  const int h = cxcd * 2 + (t >> 5);
  const int q0 = (t & 31) * 128;

  const unsigned short* Qh = Q + h * 262144;
  const unsigned short* Kh = K + h * 262144;
  const unsigned short* Vh = Vt + h * 262144;

  // Q fragments in registers: Q[q0 + w*32 + l31][d = dstep*16 + hi*8 + j]
  s16x8 qf[4];
#pragma unroll
  for (int d = 0; d < 4; ++d)
    qf[d] = *reinterpret_cast<const s16x8*>(Qh + (size_t)(q0 + w * 32 + l31) * 64 + d * 16 + hi * 8);

  // LDS fragment offsets (loop-invariant). XOR swizzle: chunk ^= (row&7).
  unsigned koff[8];   // [kt32*4 + dstep]
#pragma unroll
  for (int k2 = 0; k2 < 2; ++k2)
#pragma unroll
    for (int d = 0; d < 4; ++d) {
      int row = k2 * 32 + l31;
      int ch = (d * 2 + hi) ^ (row & 7);
      koff[k2 * 4 + d] = (unsigned)(row * 128 + ch * 16);
    }
  unsigned voff[8];   // [n*4 + ks]
#pragma unroll
  for (int n = 0; n < 2; ++n)
#pragma unroll
    for (int ks = 0; ks < 4; ++ks) {
      int row = n * 32 + l31;
      int ch = (ks * 2 + hi) ^ (row & 7);
      voff[n * 4 + ks] = (unsigned)(row * 128 + ch * 16);
    }

  // staging: global_load_lds, linear LDS dest + inverse-swizzled global source
  const int so = ((lane & 7) ^ (lane >> 3)) * 8;  // bf16 elems within row
  const int rsub = lane >> 3;
  auto stage = [&](int kt, char* buf) {
    char* bK = buf;
    char* bV = buf + 8192;
    const unsigned short* Ksrc = Kh + (size_t)kt * 4096;
    const unsigned short* Vsrc = Vh + kt * 64;
    gload16(Ksrc + (w * 16 + rsub) * 64 + so,                bK + w * 2048);
    gload16(Ksrc + (w * 16 + 8 + rsub) * 64 + so,            bK + w * 2048 + 1024);
    gload16(Vsrc + (size_t)(w * 16 + rsub) * 4096 + so,      bV + w * 2048);
    gload16(Vsrc + (size_t)(w * 16 + 8 + rsub) * 4096 + so,  bV + w * 2048 + 1024);
  };

  f32x16 o0 = {}, o1 = {};
  float rsl = 0.f;

  stage(0, smem);
  __syncthreads();

  for (int kt = 0; kt < 64; ++kt) {
    const int cur = kt & 1;
    char* cb = smem + cur * 16384;
    if (kt < 63) stage(kt + 1, smem + (cur ^ 1) * 16384);

    const char* bK = cb;
    const char* bV = cb + 8192;

    // S^T = mfma(K, Q): D[key][q], col=l31=q, row=key=(reg&3)+8*(reg>>2)+4*hi
    f32x16 s0 = {}, s1 = {};
#pragma unroll
    for (int d = 0; d < 4; ++d) {
      s16x8 a0 = *reinterpret_cast<const s16x8*>(bK + koff[d]);
      s16x8 a1 = *reinterpret_cast<const s16x8*>(bK + koff[4 + d]);
      s0 = MFMA32(a0, qf[d], s0);
      s1 = MFMA32(a1, qf[d], s1);
    }

    // P = 2^S (scale folded into Q); pack to PV A-frags in-register
    s16x8 pa[4];
    {
      float p[16];
#pragma unroll
      for (int r = 0; r < 16; ++r) { p[r] = expv(s0[r]); rsl += p[r]; }
      unsigned a0 = cvtpk(p[0], p[1]), b0 = cvtpk(p[2], p[3]);
      unsigned a1 = cvtpk(p[4], p[5]), b1 = cvtpk(p[6], p[7]);
      pl32swap(a0, a1); pl32swap(b0, b1);
      U8 f; f.u[0] = a0; f.u[1] = b0; f.u[2] = a1; f.u[3] = b1;
      pa[0] = f.h;
      a0 = cvtpk(p[8], p[9]);  b0 = cvtpk(p[10], p[11]);
      a1 = cvtpk(p[12], p[13]); b1 = cvtpk(p[14], p[15]);
      pl32swap(a0, a1); pl32swap(b0, b1);
      U8 g; g.u[0] = a0; g.u[1] = b0; g.u[2] = a1; g.u[3] = b1;
      pa[1] = g.h;
    }
    {
      float p[16];
#pragma unroll
      for (int r = 0; r < 16; ++r) { p[r] = expv(s1[r]); rsl += p[r]; }
      unsigned a0 = cvtpk(p[0], p[1]), b0 = cvtpk(p[2], p[3]);
      unsigned a1 = cvtpk(p[4], p[5]), b1 = cvtpk(p[6], p[7]);
      pl32swap(a0, a1); pl32swap(b0, b1);
      U8 f; f.u[0] = a0; f.u[1] = b0; f.u[2] = a1; f.u[3] = b1;
      pa[2] = f.h;
      a0 = cvtpk(p[8], p[9]);  b0 = cvtpk(p[10], p[11]);
      a1 = cvtpk(p[12], p[13]); b1 = cvtpk(p[14], p[15]);
      pl32swap(a0, a1); pl32swap(b0, b1);
      U8 g; g.u[0] = a0; g.u[1] = b0; g.u[2] = a1; g.u[3] = b1;
      pa[3] = g.h;
    }

    // O += P V
#pragma unroll
    for (int ks = 0; ks < 4; ++ks) {
      s16x8 v0 = *reinterpret_cast<const s16x8*>(bV + voff[ks]);
      s16x8 v1 = *reinterpret_cast<const s16x8*>(bV + voff[4 + ks]);
      o0 = MFMA32(pa[ks], v0, o0);
      o1 = MFMA32(pa[ks], v1, o1);
    }

    __syncthreads();
  }

  // row-sum across the two lane halves; reciprocal; broadcast via wave-private LDS strip
  float rst = rsl + __shfl_xor(rsl, 32, 64);
  float inv;
  asm("v_rcp_f32 %0, %1" : "=v"(inv) : "v"(rst));
  if (lane < 32) rsf[w * 32 + l31] = inv;
  __syncthreads();

#pragma unroll
  for (int reg = 0; reg < 16; ++reg) {
    int qr = (reg & 3) + 8 * (reg >> 2) + 4 * hi;
    float iv = rsf[w * 32 + qr];
    size_t base = (size_t)(q0 + w * 32 + qr) * 1024 + h * 64 + l31;
    cc[base]      = f2bf(o0[reg] * iv);
    cc[base + 32] = f2bf(o1[reg] * iv);
  }
}

// ---------------- output projection GEMM (128x128 tiles) ----------------
// grid (32, 8), 512 thr (8 waves, 2m x 4n; wave tile 64m x 32n).
__global__ __launch_bounds__(512, 4)
void out_gemm(const unsigned short* __restrict__ A,    // cc [4096][1024] bf16
              const unsigned short* __restrict__ Bt,   // wot [1024 eo][1024 k] bf16
              float* __restrict__ out) {
  __shared__ char lds[16384 + 16384];
  char* At = lds;
  char* Bl = lds + 16384;

  const int tid = threadIdx.x;
  const int w = tid >> 6, lane = tid & 63;
  const int lr = lane & 15, lg = lane >> 4;
  const int mh = w >> 2, nq = w & 3;
  const int m0 = blockIdx.x * 128;
  const int n0 = blockIdx.y * 128;

  f32x4 acc[4][2] = {};

  unsigned aoff[4][2], boff[2][2];
#pragma unroll
  for (int m = 0; m < 4; ++m) {
    int row = mh * 64 + m * 16 + lr;
#pragma unroll
    for (int ks = 0; ks < 2; ++ks)
      aoff[m][ks] = (unsigned)((row * 128 + ks * 64 + lg * 16) ^ ((row & 7) << 4));
  }
#pragma unroll
  for (int n = 0; n < 2; ++n) {
    int row = nq * 32 + n * 16 + lr;
#pragma unroll
    for (int ks = 0; ks < 2; ++ks)
      boff[n][ks] = (unsigned)((row * 128 + ks * 64 + lg * 16) ^ ((row & 7) << 4));
  }

  for (int kk = 0; kk < 16; ++kk) {
#pragma unroll
    for (int i = 0; i < 4; ++i) {
      int seg = w * 4 + i;
      int row = (seg & 15) * 8 + (lane >> 3);
      int c = lane & 7;
      if (seg < 16)
        gload16(A + (size_t)(m0 + row) * 1024 + kk * 64 + ((c ^ (row & 7)) * 8),
                At + seg * 1024);
      else
        gload16(Bt + (size_t)(n0 + row) * 1024 + kk * 64 + ((c ^ (row & 7)) * 8),
                Bl + (seg - 16) * 1024);
    }
    __syncthreads();
#pragma unroll
    for (int ks = 0; ks < 2; ++ks) {
      s16x8 af[4], bf[2];
#pragma unroll
      for (int m = 0; m < 4; ++m) af[m] = *reinterpret_cast<const s16x8*>(At + aoff[m][ks]);
#pragma unroll
      for (int n = 0; n < 2; ++n) bf[n] = *reinterpret_cast<const s16x8*>(Bl + boff[n][ks]);
#pragma unroll
      for (int m = 0; m < 4; ++m)
#pragma unroll
        for (int n = 0; n < 2; ++n)
          acc[m][n] = MFMA16(af[m], bf[n], acc[m][n]);
    }
    __syncthreads();
  }

#pragma unroll
  for (int m = 0; m < 4; ++m)
#pragma unroll
    for (int n = 0; n < 2; ++n)
#pragma unroll
      for (int r = 0; r < 4; ++r) {
        int row = m0 + mh * 64 + m * 16 + lg * 4 + r;
        int col = n0 + nq * 32 + n * 16 + lr;
        out[(size_t)row * 1024 + col] = acc[m][n][r];
      }
}

// ---------------- launcher ----------------

extern "C" void kernel_launch(void* const* d_in, const int* in_sizes, int n_in,
                              void* d_out, int out_size, void* d_ws, size_t ws_size,
                              hipStream_t stream) {
  const float* x  = (const float*)d_in[0];
  const float* Wq = (const float*)d_in[1];
  const float* Wk = (const float*)d_in[2];
  const float* Wv = (const float*)d_in[3];
  const float* Wo = (const float*)d_in[4];
  float* out = (float*)d_out;
  char* ws = (char*)d_ws;

  unsigned short* xb  = (unsigned short*)(ws);
  unsigned short* wqt = (unsigned short*)(ws + 8388608);
  unsigned short* wkt = (unsigned short*)(ws + 10485760);
  unsigned short* wvt = (unsigned short*)(ws + 12582912);
  unsigned short* wot = (unsigned short*)(ws + 14680064);
  unsigned short* Qb  = (unsigned short*)(ws + 16777216);
  unsigned short* Kb  = (unsigned short*)(ws + 25165824);
  unsigned short* Vtb = (unsigned short*)(ws + 33554432);
  unsigned short* cc  = (unsigned short*)(ws + 41943040);

  convert_x<<<4096, 256, 0, stream>>>(x, xb);
  transpose_cast<<<dim3(16, 16, 1), 256, 0, stream>>>(Wq, wqt, 1024, 64);
  transpose_cast<<<dim3(16, 16, 1), 256, 0, stream>>>(Wk, wkt, 1024, 64);
  transpose_cast<<<dim3(16, 16, 1), 256, 0, stream>>>(Wv, wvt, 1024, 64);
  transpose_cast<<<dim3(1, 16, 16), 256, 0, stream>>>(Wo, wot, 1024, 1024);

  qkv_gemm<<<dim3(32, 16), 512, 0, stream>>>(xb, wqt, wkt, wvt, Qb, Kb, Vtb);
  attn_kernel<<<512, 256, 0, stream>>>(Qb, Kb, Vtb, cc);
  out_gemm<<<dim3(32, 8), 512, 0, stream>>>(cc, wot, out);
}

// Round 10
// 228.384 us; speedup vs baseline: 1.3148x; 1.0113x over previous
//
#include <hip/hip_runtime.h>
#include <hip/hip_bf16.h>

// N=4096, E=1024, H=16, DK=DV=64
// ws layout (bytes):
//   xb  @ 0      8 MB  bf16 [4096][1024]
//   wqt @ 8 MB   2 MB  bf16 [16][64][1024]
//   wkt @ 10 MB  2 MB
//   wvt @ 12 MB  2 MB
//   wot @ 14 MB  2 MB  bf16 [1024 eo][1024 k]
//   Q   @ 16 MB  8 MB  bf16 [16][4096][64]  (scaled by 0.125*log2e)
//   K   @ 24 MB  8 MB  bf16 [16][4096][64]
//   Vt  @ 32 MB  8 MB  bf16 [16][64][4096]
//   cc  @ 40 MB  8 MB  bf16 [4096][1024]

typedef __attribute__((ext_vector_type(8))) short s16x8;
typedef __attribute__((ext_vector_type(4))) float f32x4;
typedef __attribute__((ext_vector_type(16))) float f32x16;

#define MFMA16(A, B, C) __builtin_amdgcn_mfma_f32_16x16x32_bf16((A), (B), (C), 0, 0, 0)
#define MFMA32(A, B, C) __builtin_amdgcn_mfma_f32_32x32x16_bf16((A), (B), (C), 0, 0, 0)

union U8 { s16x8 h; unsigned u[4]; };

__device__ __forceinline__ unsigned short f2bf(float f) {
  unsigned int u = __float_as_uint(f);
  unsigned int r = (u + 0x7FFFu + ((u >> 16) & 1u)) >> 16;
  return (unsigned short)r;
}

__device__ __forceinline__ float expv(float x) {  // 2^x
  float r; asm("v_exp_f32 %0, %1" : "=v"(r) : "v"(x)); return r;
}

__device__ __forceinline__ unsigned cvtpk(float lo, float hi) {
  unsigned d; asm("v_cvt_pk_bf16_f32 %0, %1, %2" : "=v"(d) : "v"(lo), "v"(hi)); return d;
}

__device__ __forceinline__ void pl32swap(unsigned& a, unsigned& b) {
  asm("v_permlane32_swap_b32 %0, %1" : "+v"(a), "+v"(b));
}

__device__ __forceinline__ void gload16(const void* g, void* l) {
  __builtin_amdgcn_global_load_lds(
      (const __attribute__((address_space(1))) unsigned*)g,
      (__attribute__((address_space(3))) unsigned*)l, 16, 0, 0);
}

// ---------------- prep kernels ----------------

__global__ __launch_bounds__(256) void convert_x(const float* __restrict__ x,
                                                 unsigned short* __restrict__ xb) {
  unsigned i = blockIdx.x * 256u + threadIdx.x;
  float4 v = reinterpret_cast<const float4*>(x)[i];
  ushort4 o;
  o.x = f2bf(v.x); o.y = f2bf(v.y); o.z = f2bf(v.z); o.w = f2bf(v.w);
  reinterpret_cast<ushort4*>(xb)[i] = o;
}

// tiled transpose+cast: src [B][R][C] f32 -> dst [B][C][R] bf16. grid (B, R/64, C/64), 256 thr.
__global__ __launch_bounds__(256)
void transpose_cast(const float* __restrict__ src, unsigned short* __restrict__ dst,
                    int R, int C) {
  __shared__ float t[64][65];
  const int b = blockIdx.x, rt = blockIdx.y, ct = blockIdx.z;
  const int q = threadIdx.x & 3;
  const float* S = src + ((size_t)b * R + rt * 64) * C + ct * 64;
  {
    const int r = threadIdx.x >> 2;
#pragma unroll
    for (int i = 0; i < 4; ++i) {
      float4 v = *reinterpret_cast<const float4*>(S + (size_t)r * C + (i * 4 + q) * 4);
      t[r][(i * 4 + q) * 4 + 0] = v.x;
      t[r][(i * 4 + q) * 4 + 1] = v.y;
      t[r][(i * 4 + q) * 4 + 2] = v.z;
      t[r][(i * 4 + q) * 4 + 3] = v.w;
    }
  }
  __syncthreads();
  const int c = threadIdx.x >> 2;
  unsigned short* D = dst + ((size_t)b * C + ct * 64 + c) * R + rt * 64;
#pragma unroll
  for (int i = 0; i < 2; ++i) {
    int rb = q * 16 + i * 8;
    union { ushort4 v[2]; unsigned short s[8]; } pk;
#pragma unroll
    for (int k = 0; k < 8; ++k) pk.s[k] = f2bf(t[rb + k][c]);
    *reinterpret_cast<ushort4*>(D + rb) = pk.v[0];
    *reinterpret_cast<ushort4*>(D + rb + 4) = pk.v[1];
  }
}

// ---------------- fused QKV projection GEMM (N=192 per head) ----------------
// grid (32 mtiles, 16 heads), 512 thr (8 waves, 2m x 4n over 128x192).
__global__ __launch_bounds__(512, 4)
void qkv_gemm(const unsigned short* __restrict__ xb,
              const unsigned short* __restrict__ wqt,
              const unsigned short* __restrict__ wkt,
              const unsigned short* __restrict__ wvt,
              unsigned short* __restrict__ Q,
              unsigned short* __restrict__ K,
              unsigned short* __restrict__ Vt) {
  __shared__ char lds[16384 + 24576];
  char* At = lds;           // [128][64] bf16, chunk ^= row&7
  char* Bl = lds + 16384;   // [192][64] bf16, chunk ^= row&7

  const int tid = threadIdx.x;
  const int w = tid >> 6, lane = tid & 63;
  const int lr = lane & 15, lg = lane >> 4;
  const int mh = w >> 2, nq = w & 3;  // wave tile: 64m x 48n
  const int h = blockIdx.y;
  const int m0 = blockIdx.x * 128;

  f32x4 acc[4][3] = {};

  unsigned aoff[4][2], boff[3][2];
#pragma unroll
  for (int m = 0; m < 4; ++m) {
    int row = mh * 64 + m * 16 + lr;
#pragma unroll
    for (int ks = 0; ks < 2; ++ks)
      aoff[m][ks] = (unsigned)((row * 128 + ks * 64 + lg * 16) ^ ((row & 7) << 4));
  }
#pragma unroll
  for (int n = 0; n < 3; ++n) {
    int row = nq * 48 + n * 16 + lr;
#pragma unroll
    for (int ks = 0; ks < 2; ++ks)
      boff[n][ks] = (unsigned)((row * 128 + ks * 64 + lg * 16) ^ ((row & 7) << 4));
  }

  for (int kk = 0; kk < 16; ++kk) {
    // stage via global_load_lds: 40 segments of 1KB; wave w does segs w*5..w*5+4
#pragma unroll
    for (int i = 0; i < 5; ++i) {
      int seg = w * 5 + i;
      if (seg < 16) {  // A
        int row = seg * 8 + (lane >> 3);
        int c = lane & 7;
        gload16(xb + (size_t)(m0 + row) * 1024 + kk * 64 + ((c ^ (row & 7)) * 8),
                At + seg * 1024);
      } else {         // B: rows 0..191 = [Wq|Wk|Wv] per head
        int s2 = seg - 16;
        int row = s2 * 8 + (lane >> 3);
        int mat = row >> 6, mr = row & 63;
        const unsigned short* Wb = (mat == 0 ? wqt : (mat == 1 ? wkt : wvt));
        int c = lane & 7;
        gload16(Wb + h * 65536 + mr * 1024 + kk * 64 + ((c ^ (row & 7)) * 8),
                Bl + s2 * 1024);
      }
    }
    __syncthreads();
#pragma unroll
    for (int ks = 0; ks < 2; ++ks) {
      s16x8 af[4], bf[3];
#pragma unroll
      for (int m = 0; m < 4; ++m) af[m] = *reinterpret_cast<const s16x8*>(At + aoff[m][ks]);
#pragma unroll
      for (int n = 0; n < 3; ++n) bf[n] = *reinterpret_cast<const s16x8*>(Bl + boff[n][ks]);
#pragma unroll
      for (int m = 0; m < 4; ++m)
#pragma unroll
        for (int n = 0; n < 3; ++n)
          acc[m][n] = MFMA16(af[m], bf[n], acc[m][n]);
    }
    __syncthreads();
  }

#pragma unroll
  for (int n = 0; n < 3; ++n) {
    int col = nq * 48 + n * 16 + lr;   // 0..191
    int mat = col >> 6, d = col & 63;
    const float sc = (mat == 0) ? 0.18033688011112042f : 1.0f;  // 0.125*log2(e)
    unsigned short* dst = (mat == 0 ? Q : (mat == 1 ? K : Vt));
#pragma unroll
    for (int m = 0; m < 4; ++m)
#pragma unroll
      for (int r = 0; r < 4; ++r) {
        int row = m0 + mh * 64 + m * 16 + lg * 4 + r;
        unsigned short val = f2bf(acc[m][n][r] * sc);
        if (mat < 2) dst[h * 262144 + row * 64 + d] = val;
        else         dst[h * 262144 + d * 4096 + row] = val;
      }
  }
}

// ---------------- fused attention: R2 structure + 2 q-subtiles per wave ----------------
// 256 blocks x 256 threads (4 waves x 64 q-rows = QBLK 256). KVBLK=64, double-buffered.
// Per wave-iter: 16 ds_read_b128 feed 32 MFMA32 (2:1 vs R2's 1:1).
#define SOFTPACK(S, PA, RS) do {                                            \
    float p_[16];                                                           \
    _Pragma("unroll")                                                       \
    for (int r_ = 0; r_ < 16; ++r_) { p_[r_] = expv((S)[r_]); RS += p_[r_]; } \
    unsigned a0_ = cvtpk(p_[0], p_[1]), b0_ = cvtpk(p_[2], p_[3]);          \
    unsigned a1_ = cvtpk(p_[4], p_[5]), b1_ = cvtpk(p_[6], p_[7]);          \
    pl32swap(a0_, a1_); pl32swap(b0_, b1_);                                 \
    U8 f_; f_.u[0] = a0_; f_.u[1] = b0_; f_.u[2] = a1_; f_.u[3] = b1_;      \
    (PA)[0] = f_.h;                                                         \
    a0_ = cvtpk(p_[8], p_[9]);  b0_ = cvtpk(p_[10], p_[11]);                \
    a1_ = cvtpk(p_[12], p_[13]); b1_ = cvtpk(p_[14], p_[15]);               \
    pl32swap(a0_, a1_); pl32swap(b0_, b1_);                                 \
    U8 g_; g_.u[0] = a0_; g_.u[1] = b0_; g_.u[2] = a1_; g_.u[3] = b1_;      \
    (PA)[1] = g_.h;                                                         \
  } while (0)

__global__ __launch_bounds__(256)
void attn_kernel(const unsigned short* __restrict__ Q,
                 const unsigned short* __restrict__ K,
                 const unsigned short* __restrict__ Vt,
                 unsigned short* __restrict__ cc) {
  __shared__ char smem[2 * 16384 + 1024];  // 2 x {K[64][64] swz, Vt[64][64] swz} + rsinv[256]
  float* rsf = reinterpret_cast<float*>(smem + 32768);

  const int tid = threadIdx.x;
  const int w = tid >> 6, lane = tid & 63;
  const int l31 = lane & 31, hi = lane >> 5;

  // XCD swizzle: 2 heads per XCD (K/V of 2 heads = 2 MB fits the 4 MB XCD L2)
  // 256 blocks: 32 per XCD = 2 heads x 16 q-chunks.
  const int lin = blockIdx.x;
  const int cxcd = lin & 7, t = lin >> 3;      // t in 0..31
  const int h = cxcd * 2 + (t >> 4);
  const int q0 = (t & 15) * 256;

  const unsigned short* Qh = Q + h * 262144;
  const unsigned short* Kh = K + h * 262144;
  const unsigned short* Vh = Vt + h * 262144;

  // Q fragments in registers: subtile A rows q0+w*64..+31, subtile B +32..+63
  s16x8 qfA[4], qfB[4];
#pragma unroll
  for (int d = 0; d < 4; ++d) {
    qfA[d] = *reinterpret_cast<const s16x8*>(Qh + (size_t)(q0 + w * 64 + l31) * 64 + d * 16 + hi * 8);
    qfB[d] = *reinterpret_cast<const s16x8*>(Qh + (size_t)(q0 + w * 64 + 32 + l31) * 64 + d * 16 + hi * 8);
  }

  // LDS fragment offsets (loop-invariant). XOR swizzle: chunk ^= (row&7). [R2-validated]
  unsigned koff[8];   // [kt32*4 + dstep]
#pragma unroll
  for (int k2 = 0; k2 < 2; ++k2)
#pragma unroll
    for (int d = 0; d < 4; ++d) {
      int row = k2 * 32 + l31;
      int ch = (d * 2 + hi) ^ (row & 7);
      koff[k2 * 4 + d] = (unsigned)(row * 128 + ch * 16);
    }
  unsigned voff[8];   // [n*4 + ks]
#pragma unroll
  for (int n = 0; n < 2; ++n)
#pragma unroll
    for (int ks = 0; ks < 4; ++ks) {
      int row = n * 32 + l31;
      int ch = (ks * 2 + hi) ^ (row & 7);
      voff[n * 4 + ks] = (unsigned)(row * 128 + ch * 16);
    }

  // staging: global_load_lds, linear LDS dest + inverse-swizzled global source [R2-validated]
  const int so = ((lane & 7) ^ (lane >> 3)) * 8;  // bf16 elems within row
  const int rsub = lane >> 3;
  auto stage = [&](int kt, char* buf) {
    char* bK = buf;
    char* bV = buf + 8192;
    const unsigned short* Ksrc = Kh + (size_t)kt * 4096;
    const unsigned short* Vsrc = Vh + kt * 64;
    gload16(Ksrc + (w * 16 + rsub) * 64 + so,                bK + w * 2048);
    gload16(Ksrc + (w * 16 + 8 + rsub) * 64 + so,            bK + w * 2048 + 1024);
    gload16(Vsrc + (size_t)(w * 16 + rsub) * 4096 + so,      bV + w * 2048);
    gload16(Vsrc + (size_t)(w * 16 + 8 + rsub) * 4096 + so,  bV + w * 2048 + 1024);
  };

  f32x16 oA0 = {}, oA1 = {}, oB0 = {}, oB1 = {};
  float rsA = 0.f, rsB = 0.f;

  stage(0, smem);
  __syncthreads();

  for (int kt = 0; kt < 64; ++kt) {
    const int cur = kt & 1;
    char* cb = smem + cur * 16384;
    if (kt < 63) stage(kt + 1, smem + (cur ^ 1) * 16384);

    const char* bK = cb;
    const char* bV = cb + 8192;

    // S^T = mfma(K, Q): K-fragments read once, reused for both q-subtiles
    f32x16 sA0 = {}, sA1 = {}, sB0 = {}, sB1 = {};
#pragma unroll
    for (int d = 0; d < 4; ++d) {
      s16x8 a0 = *reinterpret_cast<const s16x8*>(bK + koff[d]);
      s16x8 a1 = *reinterpret_cast<const s16x8*>(bK + koff[4 + d]);
      sA0 = MFMA32(a0, qfA[d], sA0);
      sA1 = MFMA32(a1, qfA[d], sA1);
      sB0 = MFMA32(a0, qfB[d], sB0);
      sB1 = MFMA32(a1, qfB[d], sB1);
    }

    // P = 2^S; pack to PV A-frags in-register
    s16x8 paA[4], paB[4];
    SOFTPACK(sA0, paA, rsA);
    SOFTPACK(sA1, paA + 2, rsA);
    SOFTPACK(sB0, paB, rsB);
    SOFTPACK(sB1, paB + 2, rsB);

    // O += P V: V-fragments read once, reused for both q-subtiles
#pragma unroll
    for (int ks = 0; ks < 4; ++ks) {
      s16x8 v0 = *reinterpret_cast<const s16x8*>(bV + voff[ks]);
      s16x8 v1 = *reinterpret_cast<const s16x8*>(bV + voff[4 + ks]);
      oA0 = MFMA32(paA[ks], v0, oA0);
      oA1 = MFMA32(paA[ks], v1, oA1);
      oB0 = MFMA32(paB[ks], v0, oB0);
      oB1 = MFMA32(paB[ks], v1, oB1);
    }

    __syncthreads();
  }

  // row-sums: combine lane halves, reciprocal, broadcast via per-wave LDS strip
  float rstA = rsA + __shfl_xor(rsA, 32, 64);
  float rstB = rsB + __shfl_xor(rsB, 32, 64);
  float invA, invB;
  asm("v_rcp_f32 %0, %1" : "=v"(invA) : "v"(rstA));
  asm("v_rcp_f32 %0, %1" : "=v"(invB) : "v"(rstB));
  if (lane < 32) {
    rsf[w * 64 + l31] = invA;
    rsf[w * 64 + 32 + l31] = invB;
  }
  __syncthreads();

#pragma unroll
  for (int reg = 0; reg < 16; ++reg) {
    int qr = (reg & 3) + 8 * (reg >> 2) + 4 * hi;
    float ivA = rsf[w * 64 + qr];
    float ivB = rsf[w * 64 + 32 + qr];
    size_t bA = (size_t)(q0 + w * 64 + qr) * 1024 + h * 64 + l31;
    size_t bB = (size_t)(q0 + w * 64 + 32 + qr) * 1024 + h * 64 + l31;
    cc[bA]      = f2bf(oA0[reg] * ivA);
    cc[bA + 32] = f2bf(oA1[reg] * ivA);
    cc[bB]      = f2bf(oB0[reg] * ivB);
    cc[bB + 32] = f2bf(oB1[reg] * ivB);
  }
}

// ---------------- output projection GEMM (128x128 tiles) ----------------
// grid (32, 8), 512 thr (8 waves, 2m x 4n; wave tile 64m x 32n).
__global__ __launch_bounds__(512, 4)
void out_gemm(const unsigned short* __restrict__ A,    // cc [4096][1024] bf16
              const unsigned short* __restrict__ Bt,   // wot [1024 eo][1024 k] bf16
              float* __restrict__ out) {
  __shared__ char lds[16384 + 16384];
  char* At = lds;
  char* Bl = lds + 16384;

  const int tid = threadIdx.x;
  const int w = tid >> 6, lane = tid & 63;
  const int lr = lane & 15, lg = lane >> 4;
  const int mh = w >> 2, nq = w & 3;
  const int m0 = blockIdx.x * 128;
  const int n0 = blockIdx.y * 128;

  f32x4 acc[4][2] = {};

  unsigned aoff[4][2], boff[2][2];
#pragma unroll
  for (int m = 0; m < 4; ++m) {
    int row = mh * 64 + m * 16 + lr;
#pragma unroll
    for (int ks = 0; ks < 2; ++ks)
      aoff[m][ks] = (unsigned)((row * 128 + ks * 64 + lg * 16) ^ ((row & 7) << 4));
  }
#pragma unroll
  for (int n = 0; n < 2; ++n) {
    int row = nq * 32 + n * 16 + lr;
#pragma unroll
    for (int ks = 0; ks < 2; ++ks)
      boff[n][ks] = (unsigned)((row * 128 + ks * 64 + lg * 16) ^ ((row & 7) << 4));
  }

  for (int kk = 0; kk < 16; ++kk) {
#pragma unroll
    for (int i = 0; i < 4; ++i) {
      int seg = w * 4 + i;
      int row = (seg & 15) * 8 + (lane >> 3);
      int c = lane & 7;
      if (seg < 16)
        gload16(A + (size_t)(m0 + row) * 1024 + kk * 64 + ((c ^ (row & 7)) * 8),
                At + seg * 1024);
      else
        gload16(Bt + (size_t)(n0 + row) * 1024 + kk * 64 + ((c ^ (row & 7)) * 8),
                Bl + (seg - 16) * 1024);
    }
    __syncthreads();
#pragma unroll
    for (int ks = 0; ks < 2; ++ks) {
      s16x8 af[4], bf[2];
#pragma unroll
      for (int m = 0; m < 4; ++m) af[m] = *reinterpret_cast<const s16x8*>(At + aoff[m][ks]);
#pragma unroll
      for (int n = 0; n < 2; ++n) bf[n] = *reinterpret_cast<const s16x8*>(Bl + boff[n][ks]);
#pragma unroll
      for (int m = 0; m < 4; ++m)
#pragma unroll
        for (int n = 0; n < 2; ++n)
          acc[m][n] = MFMA16(af[m], bf[n], acc[m][n]);
    }
    __syncthreads();
  }

#pragma unroll
  for (int m = 0; m < 4; ++m)
#pragma unroll
    for (int n = 0; n < 2; ++n)
#pragma unroll
      for (int r = 0; r < 4; ++r) {
        int row = m0 + mh * 64 + m * 16 + lg * 4 + r;
        int col = n0 + nq * 32 + n * 16 + lr;
        out[(size_t)row * 1024 + col] = acc[m][n][r];
      }
}

// ---------------- launcher ----------------

extern "C" void kernel_launch(void* const* d_in, const int* in_sizes, int n_in,
                              void* d_out, int out_size, void* d_ws, size_t ws_size,
                              hipStream_t stream) {
  const float* x  = (const float*)d_in[0];
  const float* Wq = (const float*)d_in[1];
  const float* Wk = (const float*)d_in[2];
  const float* Wv = (const float*)d_in[3];
  const float* Wo = (const float*)d_in[4];
  float* out = (float*)d_out;
  char* ws = (char*)d_ws;

  unsigned short* xb  = (unsigned short*)(ws);
  unsigned short* wqt = (unsigned short*)(ws + 8388608);
  unsigned short* wkt = (unsigned short*)(ws + 10485760);
  unsigned short* wvt = (unsigned short*)(ws + 12582912);
  unsigned short* wot = (unsigned short*)(ws + 14680064);
  unsigned short* Qb  = (unsigned short*)(ws + 16777216);
  unsigned short* Kb  = (unsigned short*)(ws + 25165824);
  unsigned short* Vtb = (unsigned short*)(ws + 33554432);
  unsigned short* cc  = (unsigned short*)(ws + 41943040);

  convert_x<<<4096, 256, 0, stream>>>(x, xb);
  transpose_cast<<<dim3(16, 16, 1), 256, 0, stream>>>(Wq, wqt, 1024, 64);
  transpose_cast<<<dim3(16, 16, 1), 256, 0, stream>>>(Wk, wkt, 1024, 64);
  transpose_cast<<<dim3(16, 16, 1), 256, 0, stream>>>(Wv, wvt, 1024, 64);
  transpose_cast<<<dim3(1, 16, 16), 256, 0, stream>>>(Wo, wot, 1024, 1024);

  qkv_gemm<<<dim3(32, 16), 512, 0, stream>>>(xb, wqt, wkt, wvt, Qb, Kb, Vtb);
  attn_kernel<<<256, 256, 0, stream>>>(Qb, Kb, Vtb, cc);
  out_gemm<<<dim3(32, 8), 512, 0, stream>>>(cc, wot, out);
}